// Round 7
// baseline (449.526 us; speedup 1.0000x reference)
//
#include <hip/hip_runtime.h>
#include <math.h>

typedef __bf16 bf16;
typedef __bf16 bf16x4 __attribute__((ext_vector_type(4)));
typedef __bf16 bf16x8 __attribute__((ext_vector_type(8)));
typedef float f32x4 __attribute__((ext_vector_type(4)));
typedef unsigned short u16;
typedef u16 u16x2 __attribute__((ext_vector_type(2)));

#define LOG2E 1.4426950408889634f

__device__ __forceinline__ float b2f(u16 b) {
  return (float)__builtin_bit_cast(bf16, b);
}

// ---------------------------------------------------------------------------
// dtype sniff (wave-parallel): packed-bf16 words have bits14..7 = bf16
// exponent (~[118,130]); f32 words have uniform mantissa bits there.
// ---------------------------------------------------------------------------
__global__ void sniff_k(const unsigned* __restrict__ xw_, int* __restrict__ flag) {
  int lane = threadIdx.x;  // 64 threads
  int c = 0;
#pragma unroll
  for (int j = 0; j < 4; j++) {
    unsigned e = (xw_[lane * 4 + j] >> 7) & 0xFFu;
    c += (e >= 100u && e <= 140u) ? 1 : 0;
  }
#pragma unroll
  for (int d = 1; d < 64; d <<= 1) c += __shfl_xor(c, d);
  if (lane == 0) *flag = (c >= 150) ? 1 : 0;
}

__global__ __launch_bounds__(256) void canon_big_k(const void* __restrict__ src,
                                                   bf16* __restrict__ dst,
                                                   const int* __restrict__ flag) {
  int i = (blockIdx.x * 256 + threadIdx.x) * 8;
  if (*flag) {
    *(bf16x8*)&dst[i] = *(const bf16x8*)((const bf16*)src + i);
  } else {
    const float* s = (const float*)src + i;
    bf16x8 v;
#pragma unroll
    for (int j = 0; j < 8; j++) v[j] = (bf16)s[j];
    *(bf16x8*)&dst[i] = v;
  }
}

struct CanonArgs {
  const void* src[13];
  bf16* dst[13];
  int n[13];
};

__global__ __launch_bounds__(256) void canon_small_k(CanonArgs a,
                                                     const int* __restrict__ flag) {
  int ti = blockIdx.y;
  int i = blockIdx.x * 256 + threadIdx.x;
  if (i >= a.n[ti]) return;
  if (*flag)
    a.dst[ti][i] = ((const bf16*)a.src[ti])[i];
  else
    a.dst[ti][i] = (bf16)((const float*)a.src[ti])[i];
}

// ---------------------------------------------------------------------------
// rpe gather, pre-scaled by log2(e) for exp2-domain softmax:
// rpe[h][q][m] = rel_bias[rel_index[q*512+m]][h] * log2e
// ---------------------------------------------------------------------------
__global__ __launch_bounds__(256) void rpe_k(const int* __restrict__ ridx,
                                             const bf16* __restrict__ rbias,
                                             bf16* __restrict__ rpe) {
  int t = blockIdx.x * 256 + threadIdx.x;  // 2^20 threads
  int m = t & 511, q = (t >> 9) & 511, h = t >> 18;
  rpe[t] = (bf16)((float)rbias[ridx[q * 512 + m] * 4 + h] * LOG2E);
}

// ---------------------------------------------------------------------------
// LayerNorm. ROLL=1: read x at roll(-4)+window-partition source, write window
// layout. ROLL=0: linear in/out. One wave per token (C=128), packed u32 I/O.
// ---------------------------------------------------------------------------
template <int ROLL>
__global__ __launch_bounds__(256) void ln_k(const bf16* __restrict__ x,
                                            const bf16* __restrict__ g,
                                            const bf16* __restrict__ bsh,
                                            bf16* __restrict__ out) {
  int wave = threadIdx.x >> 6, lane = threadIdx.x & 63;
  int tok = blockIdx.x * 4 + wave;
  size_t src;
  if (ROLL) {
    int win = tok >> 9, pos = tok & 511;
    int rd = (win >> 6) * 8 + (pos >> 6);
    int rh = ((win >> 3) & 7) * 8 + ((pos >> 3) & 7);
    int rw = (win & 7) * 8 + (pos & 7);
    int od = (rd + 4) & 15, oh = (rh + 4) & 63, ow = (rw + 4) & 63;
    src = (size_t)((od * 64 + oh) * 64 + ow) * 128;
  } else {
    src = (size_t)tok * 128;
  }
  int ch = lane * 2;
  u16x2 xv = *(const u16x2*)(x + src + ch);
  float f0 = b2f(xv[0]), f1 = b2f(xv[1]);
  float s = f0 + f1, sq = f0 * f0 + f1 * f1;
#pragma unroll
  for (int d = 1; d < 64; d <<= 1) {
    s += __shfl_xor(s, d);
    sq += __shfl_xor(sq, d);
  }
  float mean = s * (1.f / 128.f);
  float var = sq * (1.f / 128.f) - mean * mean;
  float rstd = rsqrtf(fmaxf(var, 0.f) + 1e-5f);
  u16x2 gv = *(const u16x2*)(g + ch), bv = *(const u16x2*)(bsh + ch);
  u16x2 ov;
  ov[0] = __builtin_bit_cast(u16, (bf16)((f0 - mean) * rstd * b2f(gv[0]) + b2f(bv[0])));
  ov[1] = __builtin_bit_cast(u16, (bf16)((f1 - mean) * rstd * b2f(gv[1]) + b2f(bv[1])));
  *(u16x2*)(out + (size_t)tok * 128 + ch) = ov;
}

// ---------------------------------------------------------------------------
// bf16 MFMA GEMM: C[M,N] = A[M,K] @ B[N,K]^T + bias[N] (+ epilogue)
// BM=BN=128, BK=64. A-tile register double-buffer across K-chunks (A streams
// HBM; B is L2-hot). VGPR->ds_write staging (global_load_lds raced in R3).
// EPI: 0 = qkv (q scale*log2e, head-major scatter), 1 = proj (win-rev+roll+
//      resid), 2 = mlp1 (tanh-gelu, exp2-based), 3 = mlp2 (resid; flagged out)
// ---------------------------------------------------------------------------
template <int EPI, int N_, int K_>
__global__ __launch_bounds__(256) void gemm_k(const bf16* __restrict__ A,
                                              const bf16* __restrict__ B,
                                              const bf16* __restrict__ bias,
                                              void* __restrict__ outv,
                                              const bf16* __restrict__ resid,
                                              const int* __restrict__ flag) {
  __shared__ __align__(16) u16 As[128 * 72];
  __shared__ __align__(16) u16 Bs[128 * 72];
  const int t = threadIdx.x;
  const int wave = t >> 6, lane = t & 63, l15 = lane & 15, quad = lane >> 4;
  const int m0 = blockIdx.x * 128, n0 = blockIdx.y * 128;
  int fl = 0;
  if constexpr (EPI == 3) fl = *flag;
  f32x4 acc[4][4] = {};
  const int wr = (wave >> 1) * 64, wc = (wave & 1) * 64;
  const int srow = t >> 3, scol = (t & 7) * 8;  // 32 rows per 256-thread pass
  constexpr int NC = K_ / 64;
  bf16x8 avA[4], avB[4];
#pragma unroll
  for (int p = 0; p < 4; p++) {
    int row = p * 32 + srow;
    avA[p] = *(const bf16x8*)(A + (size_t)(m0 + row) * K_ + scol);
  }
#pragma unroll
  for (int c = 0; c < NC; c++) {
    const bf16x8* av = (c & 1) ? avB : avA;
    bf16x8* avN = (c & 1) ? avA : avB;
    if (c + 1 < NC) {  // prefetch next A chunk (overlaps this chunk's compute)
#pragma unroll
      for (int p = 0; p < 4; p++) {
        int row = p * 32 + srow;
        avN[p] = *(const bf16x8*)(A + (size_t)(m0 + row) * K_ + (c + 1) * 64 + scol);
      }
    }
    bf16x8 bv[4];
#pragma unroll
    for (int p = 0; p < 4; p++) {
      int row = p * 32 + srow;
      bv[p] = *(const bf16x8*)(B + (size_t)(n0 + row) * K_ + c * 64 + scol);
    }
    __syncthreads();  // prev iter's LDS reads done
#pragma unroll
    for (int p = 0; p < 4; p++) {
      int row = p * 32 + srow;
      *(bf16x8*)&As[row * 72 + scol] = av[p];
      *(bf16x8*)&Bs[row * 72 + scol] = bv[p];
    }
    __syncthreads();
#pragma unroll
    for (int ks = 0; ks < 2; ks++) {
      bf16x8 a[4], b[4];
#pragma unroll
      for (int i = 0; i < 4; i++) {
        a[i] = *(const bf16x8*)&As[(wr + i * 16 + l15) * 72 + ks * 32 + quad * 8];
        b[i] = *(const bf16x8*)&Bs[(wc + i * 16 + l15) * 72 + ks * 32 + quad * 8];
      }
#pragma unroll
      for (int i = 0; i < 4; i++)
#pragma unroll
        for (int j = 0; j < 4; j++)
          acc[i][j] =
              __builtin_amdgcn_mfma_f32_16x16x32_bf16(a[i], b[j], acc[i][j], 0, 0, 0);
    }
  }
  // q scale folded with log2e for exp2-domain softmax downstream
  const float qscale = 0.17677669529663687f * LOG2E;
#pragma unroll
  for (int i = 0; i < 4; i++) {
#pragma unroll
    for (int r = 0; r < 4; r++) {
      int tok = m0 + wr + i * 16 + quad * 4 + r;
      size_t obase = 0;
      if constexpr (EPI == 1) {
        int win = tok >> 9, pos = tok & 511;
        int rd = (win >> 6) * 8 + (pos >> 6);
        int rh = ((win >> 3) & 7) * 8 + ((pos >> 3) & 7);
        int rw = (win & 7) * 8 + (pos & 7);
        int od = (rd + 4) & 15, oh = (rh + 4) & 63, ow = (rw + 4) & 63;
        obase = (size_t)((od * 64 + oh) * 64 + ow) * 128;
      } else if constexpr (EPI != 0) {
        obase = (size_t)tok * N_;
      }
#pragma unroll
      for (int j = 0; j < 4; j++) {
        int gn = n0 + wc + j * 16 + l15;
        float v = acc[i][j][r] + (float)bias[gn];
        if constexpr (EPI == 0) {
          int tensor = gn >> 7, c = gn & 127, head = c >> 5, d = c & 31;
          if (tensor == 0) v *= qscale;
          int win = tok >> 9, pos = tok & 511;
          size_t off = ((((size_t)tensor * 4 + head) * 128 + win) * 512 + pos) * 32 + d;
          ((bf16*)outv)[off] = (bf16)v;
        } else if constexpr (EPI == 1) {
          v += (float)resid[obase + gn];
          ((bf16*)outv)[obase + gn] = (bf16)v;
        } else if constexpr (EPI == 2) {
          // tanh-GELU via native exp2: g = v - v/(exp2(u2)+1),
          // u2 = (2*0.7978845608*(v + 0.044715 v^3)) * log2e
          float v2 = v * v;
          float u2 = v * (2.30220806f + 0.10294323f * v2);
          float e2 = exp2f(u2);
          float rcp = __builtin_amdgcn_rcpf(e2 + 1.f);
          v = v - v * rcp;
          ((bf16*)outv)[obase + gn] = (bf16)v;
        } else {
          v += (float)resid[obase + gn];
          if (fl)
            ((bf16*)outv)[obase + gn] = (bf16)v;
          else
            ((float*)outv)[obase + gn] = v;
        }
      }
    }
  }
}

// ---------------------------------------------------------------------------
// Fused window attention, S^T formulation, exp2-domain softmax, half-V
// staging (keys 0-255 then 256-511) -> 36 KB LDS, 3 barriers total.
// Block = (window, head, 128-query chunk). qkv head-major
// [tensor][head][win][pos][32]. kt loop unrolled 2x so K/rpe loads of kt+1
// overlap softmax of kt.
// ---------------------------------------------------------------------------
__global__ __launch_bounds__(256) void attn_k(const bf16* __restrict__ qkv,
                                              const bf16* __restrict__ rpe,
                                              bf16* __restrict__ att) {
  __shared__ __align__(16) bf16 sVt[32 * 264];   // V^T [d][key-half], 264=256+8
  __shared__ __align__(16) bf16 sP[4][32 * 72];  // per-wave P^T [q][key]
  __shared__ __align__(4) unsigned char lbl[512];
  const int t = threadIdx.x;
  const int p = blockIdx.x;
  const int win = ((p >> 7) << 3) | (p & 7);
  const int j = (p >> 3) & 15;
  const int head = j >> 2, qc = j & 3;
  const int wave = t >> 6, lane = t & 63, l15 = lane & 15, quad = lane >> 4;

  const int wd = win >> 6, wh = (win >> 3) & 7, ww = win & 7;
  const bool wm = (wd == 1) || (wh == 7) || (ww == 7);  // boundary window?
  if (wm) {  // region labels: per-axis boundaries at size-8, size-4
    for (int pp = t; pp < 512; pp += 256) {
      int gd = wd * 8 + (pp >> 6), gh = wh * 8 + ((pp >> 3) & 7),
          gw = ww * 8 + (pp & 7);
      int ld = gd < 8 ? 0 : (gd < 12 ? 1 : 2);
      int lh = gh < 56 ? 0 : (gh < 60 ? 1 : 2);
      int lw = gw < 56 ? 0 : (gw < 60 ? 1 : 2);
      lbl[pp] = (unsigned char)((ld << 4) | (lh << 2) | lw);
    }
  }

  const size_t hw32 = (size_t)512 * 32;
  const bf16* qp = qkv + ((size_t)(0 * 4 + head) * 128 + win) * hw32;
  const bf16* kp = qkv + ((size_t)(1 * 4 + head) * 128 + win) * hw32;
  const bf16* vp = qkv + ((size_t)(2 * 4 + head) * 128 + win) * hw32;
  const bf16* rpeh = rpe + (size_t)head * 512 * 512;
  const int qbase = qc * 128 + wave * 32;

  // Q fragments (B operand): lane n=l15 -> query, k=quad*8+j -> d
  bf16x8 qa[2];
#pragma unroll
  for (int nt = 0; nt < 2; nt++)
    qa[nt] = *(const bf16x8*)(qp + (size_t)(qbase + nt * 16 + l15) * 32 + quad * 8);

  f32x4 O[2][2] = {};  // O^T tiles [dm][nt]
  float ms[2] = {-1e30f, -1e30f}, ls[2] = {0.f, 0.f};
  int lq[2] = {0, 0};
  bf16* pw = sP[wave];

  for (int half = 0; half < 2; half++) {
    if (half) __syncthreads();  // all waves done reading sVt of prev half
    {  // stage V^T for keys [half*256, half*256+256): paired-key u32 writes
      int kpi = t >> 3, dblk = (t & 7) * 4;
      unsigned* s32 = (unsigned*)sVt;
#pragma unroll
      for (int kb = 0; kb < 4; kb++) {
        const bf16* v0 = vp + (size_t)(half * 256 + kb * 64 + 2 * kpi) * 32 + dblk;
        bf16x4 a = *(const bf16x4*)v0;
        bf16x4 b = *(const bf16x4*)(v0 + 32);
        int keyw = kb * 32 + kpi;  // u32 index within row
#pragma unroll
        for (int dd = 0; dd < 4; dd++) {
          unsigned wv = (unsigned)__builtin_bit_cast(u16, a[dd]) |
                        ((unsigned)__builtin_bit_cast(u16, b[dd]) << 16);
          s32[(dblk + dd) * 132 + keyw] = wv;
        }
      }
    }
    __syncthreads();
    if (half == 0 && wm) {
#pragma unroll
      for (int nt = 0; nt < 2; nt++) lq[nt] = lbl[qbase + nt * 16 + l15];
    }

#pragma unroll 2
    for (int kt4 = 0; kt4 < 4; kt4++) {
      const int kt = half * 4 + kt4;
      // S^T = K·Q^T with C initialized to rpe (+mask). A=K frags from global.
      f32x4 S[4][2];
#pragma unroll
      for (int mt = 0; mt < 4; mt++) {
        bf16x8 kb =
            *(const bf16x8*)(kp + (size_t)(kt * 64 + mt * 16 + l15) * 32 + quad * 8);
        int kcb = kt * 64 + mt * 16 + quad * 4;
        unsigned kl4 = 0;
        if (wm) kl4 = *(const unsigned*)&lbl[kcb];
#pragma unroll
        for (int nt = 0; nt < 2; nt++) {
          bf16x4 rv =
              *(const bf16x4*)(rpeh + (size_t)(qbase + nt * 16 + l15) * 512 + kcb);
          f32x4 c;
#pragma unroll
          for (int r = 0; r < 4; r++) {
            float bv = (float)rv[r];
            if (wm && (int)((kl4 >> (8 * r)) & 0xFF) != lq[nt]) bv -= 144.269504f;
            c[r] = bv;
          }
          S[mt][nt] = __builtin_amdgcn_mfma_f32_16x16x32_bf16(kb, qa[nt], c, 0, 0, 0);
        }
      }
      // online softmax (exp2 domain): query = l15; keys over (mt, r, quad)
#pragma unroll
      for (int nt = 0; nt < 2; nt++) {
        float mx = -1e30f;
#pragma unroll
        for (int mt = 0; mt < 4; mt++)
#pragma unroll
          for (int r = 0; r < 4; r++) mx = fmaxf(mx, S[mt][nt][r]);
        mx = fmaxf(mx, __shfl_xor(mx, 16));
        mx = fmaxf(mx, __shfl_xor(mx, 32));
        float mnew = fmaxf(ms[nt], mx);
        float alpha = exp2f(ms[nt] - mnew);
        ms[nt] = mnew;
        float rs = 0.f;
#pragma unroll
        for (int mt = 0; mt < 4; mt++)
#pragma unroll
          for (int r = 0; r < 4; r++) {
            float pe = exp2f(S[mt][nt][r] - mnew);
            S[mt][nt][r] = pe;
            rs += pe;
          }
        rs += __shfl_xor(rs, 16);
        rs += __shfl_xor(rs, 32);
        ls[nt] = ls[nt] * alpha + rs;
        O[0][nt] *= alpha;
        O[1][nt] *= alpha;
      }
      // P store: lane holds (query=l15, 4 consecutive keys) -> b64 packed
#pragma unroll
      for (int nt = 0; nt < 2; nt++)
#pragma unroll
        for (int mt = 0; mt < 4; mt++) {
          bf16x4 pv;
#pragma unroll
          for (int r = 0; r < 4; r++) pv[r] = (bf16)S[mt][nt][r];
          *(bf16x4*)&pw[(nt * 16 + l15) * 72 + mt * 16 + quad * 4] = pv;
        }
      // O^T += V^T · P  (sVt read-only within half; pw per-wave)
#pragma unroll
      for (int s = 0; s < 2; s++) {
        bf16x8 va0 =
            *(const bf16x8*)&sVt[l15 * 264 + kt4 * 64 + s * 32 + quad * 8];
        bf16x8 va1 =
            *(const bf16x8*)&sVt[(16 + l15) * 264 + kt4 * 64 + s * 32 + quad * 8];
        bf16x8 pb0 = *(const bf16x8*)&pw[l15 * 72 + s * 32 + quad * 8];
        bf16x8 pb1 = *(const bf16x8*)&pw[(16 + l15) * 72 + s * 32 + quad * 8];
        O[0][0] = __builtin_amdgcn_mfma_f32_16x16x32_bf16(va0, pb0, O[0][0], 0, 0, 0);
        O[0][1] = __builtin_amdgcn_mfma_f32_16x16x32_bf16(va0, pb1, O[0][1], 0, 0, 0);
        O[1][0] = __builtin_amdgcn_mfma_f32_16x16x32_bf16(va1, pb0, O[1][0], 0, 0, 0);
        O[1][1] = __builtin_amdgcn_mfma_f32_16x16x32_bf16(va1, pb1, O[1][1], 0, 0, 0);
      }
    }
  }
  // epilogue: lane = query l15, regs = d (quad*4+r) -> b64 writes
#pragma unroll
  for (int nt = 0; nt < 2; nt++) {
    float inv = __builtin_amdgcn_rcpf(ls[nt]);
    int q = qbase + nt * 16 + l15;
#pragma unroll
    for (int dm = 0; dm < 2; dm++) {
      bf16x4 o;
#pragma unroll
      for (int r = 0; r < 4; r++) o[r] = (bf16)(O[dm][nt][r] * inv);
      *(bf16x4*)(att + ((size_t)win * 512 + q) * 128 + head * 32 + dm * 16 +
                 quad * 4) = o;
    }
  }
}

// ---------------------------------------------------------------------------
extern "C" void kernel_launch(void* const* d_in, const int* in_sizes, int n_in,
                              void* d_out, int out_size, void* d_ws,
                              size_t ws_size, hipStream_t stream) {
  const int* rel_index = (const int*)d_in[2];
  char* w = (char*)d_ws;

  int* flag = (int*)w;
  bf16* rb_c = (bf16*)(w + (64ull << 10));
  bf16* qw_c = (bf16*)(w + (128ull << 10));
  bf16* pw_c = (bf16*)(w + (256ull << 10));
  bf16* w1_c = (bf16*)(w + (320ull << 10));
  bf16* w2_c = (bf16*)(w + (512ull << 10));
  bf16* qb_c = (bf16*)(w + (704ull << 10));
  bf16* pb_c = (bf16*)(w + (708ull << 10));
  bf16* g1_c = (bf16*)(w + (712ull << 10));
  bf16* b1n_c = (bf16*)(w + (716ull << 10));
  bf16* g2_c = (bf16*)(w + (720ull << 10));
  bf16* b2n_c = (bf16*)(w + (724ull << 10));
  bf16* mb1_c = (bf16*)(w + (728ull << 10));
  bf16* mb2_c = (bf16*)(w + (732ull << 10));
  bf16* x_c = (bf16*)(w + (1ull << 20));    // [1,17) MB
  bf16* xw = (bf16*)(w + (17ull << 20));    // [17,33) MB; reused: att, h2
  bf16* qkvb = (bf16*)(w + (33ull << 20));  // [33,97) MB; reused: a1
  bf16* rpe = (bf16*)(w + (97ull << 20));   // [97,99) MB
  bf16* x2 = (bf16*)(w + (99ull << 20));    // [99,115) MB
  bf16* att = xw;
  bf16* h2 = xw;
  bf16* a1 = qkvb;

  sniff_k<<<1, 64, 0, stream>>>((const unsigned*)d_in[0], flag);
  canon_big_k<<<4096, 256, 0, stream>>>(d_in[0], x_c, flag);

  CanonArgs ca;
  const int srcidx[13] = {3, 4, 5, 6, 7, 8, 9, 10, 11, 12, 13, 14, 15};
  bf16* dsts[13] = {rb_c, qw_c, qb_c, pw_c, pb_c, g1_c, b1n_c,
                    g2_c, b2n_c, w1_c, mb1_c, w2_c, mb2_c};
  for (int i = 0; i < 13; i++) {
    ca.src[i] = d_in[srcidx[i]];
    ca.dst[i] = dsts[i];
    ca.n[i] = in_sizes[srcidx[i]];
  }
  canon_small_k<<<dim3(256, 13), 256, 0, stream>>>(ca, flag);

  rpe_k<<<4096, 256, 0, stream>>>(rel_index, rb_c, rpe);
  ln_k<1><<<16384, 256, 0, stream>>>(x_c, g1_c, b1n_c, xw);
  gemm_k<0, 384, 128><<<dim3(512, 3), 256, 0, stream>>>(xw, qw_c, qb_c, qkvb,
                                                        nullptr, flag);
  attn_k<<<2048, 256, 0, stream>>>(qkvb, rpe, att);
  gemm_k<1, 128, 128><<<dim3(512, 1), 256, 0, stream>>>(att, pw_c, pb_c, x2,
                                                        x_c, flag);
  ln_k<0><<<16384, 256, 0, stream>>>(x2, g2_c, b2n_c, h2);
  gemm_k<2, 512, 128><<<dim3(512, 4), 256, 0, stream>>>(h2, w1_c, mb1_c, a1,
                                                        nullptr, flag);
  gemm_k<3, 128, 512><<<dim3(512, 1), 256, 0, stream>>>(a1, w2_c, mb2_c, d_out,
                                                        x2, flag);
}

// Round 8
// 426.051 us; speedup vs baseline: 1.0551x; 1.0551x over previous
//
#include <hip/hip_runtime.h>
#include <math.h>

typedef __bf16 bf16;
typedef __bf16 bf16x4 __attribute__((ext_vector_type(4)));
typedef __bf16 bf16x8 __attribute__((ext_vector_type(8)));
typedef float f32x4 __attribute__((ext_vector_type(4)));
typedef unsigned short u16;
typedef u16 u16x2 __attribute__((ext_vector_type(2)));

#define LOG2E 1.4426950408889634f

__device__ __forceinline__ float b2f(u16 b) {
  return (float)__builtin_bit_cast(bf16, b);
}

// ---------------------------------------------------------------------------
// dtype sniff (wave-parallel): packed-bf16 words have bits14..7 = bf16
// exponent (~[118,130]); f32 words have uniform mantissa bits there.
// ---------------------------------------------------------------------------
__global__ void sniff_k(const unsigned* __restrict__ xw_, int* __restrict__ flag) {
  int lane = threadIdx.x;  // 64 threads
  int c = 0;
#pragma unroll
  for (int j = 0; j < 4; j++) {
    unsigned e = (xw_[lane * 4 + j] >> 7) & 0xFFu;
    c += (e >= 100u && e <= 140u) ? 1 : 0;
  }
#pragma unroll
  for (int d = 1; d < 64; d <<= 1) c += __shfl_xor(c, d);
  if (lane == 0) *flag = (c >= 150) ? 1 : 0;
}

__global__ __launch_bounds__(256) void canon_big_k(const void* __restrict__ src,
                                                   bf16* __restrict__ dst,
                                                   const int* __restrict__ flag) {
  int i = (blockIdx.x * 256 + threadIdx.x) * 8;
  if (*flag) {
    *(bf16x8*)&dst[i] = *(const bf16x8*)((const bf16*)src + i);
  } else {
    const float* s = (const float*)src + i;
    bf16x8 v;
#pragma unroll
    for (int j = 0; j < 8; j++) v[j] = (bf16)s[j];
    *(bf16x8*)&dst[i] = v;
  }
}

struct CanonArgs {
  const void* src[13];
  bf16* dst[13];
  int n[13];
};

__global__ __launch_bounds__(256) void canon_small_k(CanonArgs a,
                                                     const int* __restrict__ flag) {
  int ti = blockIdx.y;
  int i = blockIdx.x * 256 + threadIdx.x;
  if (i >= a.n[ti]) return;
  if (*flag)
    a.dst[ti][i] = ((const bf16*)a.src[ti])[i];
  else
    a.dst[ti][i] = (bf16)((const float*)a.src[ti])[i];
}

// ---------------------------------------------------------------------------
// rpe gather, pre-scaled by log2(e) for exp2-domain softmax:
// rpe[h][q][m] = rel_bias[rel_index[q*512+m]][h] * log2e
// ---------------------------------------------------------------------------
__global__ __launch_bounds__(256) void rpe_k(const int* __restrict__ ridx,
                                             const bf16* __restrict__ rbias,
                                             bf16* __restrict__ rpe) {
  int t = blockIdx.x * 256 + threadIdx.x;  // 2^20 threads
  int m = t & 511, q = (t >> 9) & 511, h = t >> 18;
  rpe[t] = (bf16)((float)rbias[ridx[q * 512 + m] * 4 + h] * LOG2E);
}

// ---------------------------------------------------------------------------
// LayerNorm. ROLL=1: read x at roll(-4)+window-partition source, write window
// layout. ROLL=0: linear in/out. One wave per token (C=128), packed u32 I/O.
// ---------------------------------------------------------------------------
template <int ROLL>
__global__ __launch_bounds__(256) void ln_k(const bf16* __restrict__ x,
                                            const bf16* __restrict__ g,
                                            const bf16* __restrict__ bsh,
                                            bf16* __restrict__ out) {
  int wave = threadIdx.x >> 6, lane = threadIdx.x & 63;
  int tok = blockIdx.x * 4 + wave;
  size_t src;
  if (ROLL) {
    int win = tok >> 9, pos = tok & 511;
    int rd = (win >> 6) * 8 + (pos >> 6);
    int rh = ((win >> 3) & 7) * 8 + ((pos >> 3) & 7);
    int rw = (win & 7) * 8 + (pos & 7);
    int od = (rd + 4) & 15, oh = (rh + 4) & 63, ow = (rw + 4) & 63;
    src = (size_t)((od * 64 + oh) * 64 + ow) * 128;
  } else {
    src = (size_t)tok * 128;
  }
  int ch = lane * 2;
  u16x2 xv = *(const u16x2*)(x + src + ch);
  float f0 = b2f(xv[0]), f1 = b2f(xv[1]);
  float s = f0 + f1, sq = f0 * f0 + f1 * f1;
#pragma unroll
  for (int d = 1; d < 64; d <<= 1) {
    s += __shfl_xor(s, d);
    sq += __shfl_xor(sq, d);
  }
  float mean = s * (1.f / 128.f);
  float var = sq * (1.f / 128.f) - mean * mean;
  float rstd = rsqrtf(fmaxf(var, 0.f) + 1e-5f);
  u16x2 gv = *(const u16x2*)(g + ch), bv = *(const u16x2*)(bsh + ch);
  u16x2 ov;
  ov[0] = __builtin_bit_cast(u16, (bf16)((f0 - mean) * rstd * b2f(gv[0]) + b2f(bv[0])));
  ov[1] = __builtin_bit_cast(u16, (bf16)((f1 - mean) * rstd * b2f(gv[1]) + b2f(bv[1])));
  *(u16x2*)(out + (size_t)tok * 128 + ch) = ov;
}

// ---------------------------------------------------------------------------
// bf16 MFMA GEMM: C[M,N] = A[M,K] @ B[N,K]^T + bias[N] (+ epilogue)
// BM in {128,64}, BN=128, BK=64. A-tile register double-buffer across
// K-chunks. VGPR->ds_write staging (global_load_lds raced in R3).
// BM=64 variant doubles the grid for proj/mlp2 (was 2 blocks/CU -> 4).
// EPI: 0 = qkv (q scale*log2e, head-major scatter), 1 = proj (win-rev+roll+
//      resid), 2 = mlp1 (tanh-gelu, exp2-based), 3 = mlp2 (resid; flagged out)
// ---------------------------------------------------------------------------
template <int EPI, int BM, int N_, int K_>
__global__ __launch_bounds__(256) void gemm_k(const bf16* __restrict__ A,
                                              const bf16* __restrict__ B,
                                              const bf16* __restrict__ bias,
                                              void* __restrict__ outv,
                                              const bf16* __restrict__ resid,
                                              const int* __restrict__ flag) {
  __shared__ __align__(16) u16 As[BM * 72];
  __shared__ __align__(16) u16 Bs[128 * 72];
  const int t = threadIdx.x;
  const int wave = t >> 6, lane = t & 63, l15 = lane & 15, quad = lane >> 4;
  const int m0 = blockIdx.x * BM, n0 = blockIdx.y * 128;
  constexpr int MI = BM / 32;       // m-frags per wave
  constexpr int PA = BM / 32;       // A staging passes
  int fl = 0;
  if constexpr (EPI == 3) fl = *flag;
  f32x4 acc[MI][4] = {};
  const int wr = (wave >> 1) * (BM / 2), wc = (wave & 1) * 64;
  const int srow = t >> 3, scol = (t & 7) * 8;  // 32 rows per 256-thread pass
  constexpr int NC = K_ / 64;
  bf16x8 avA[PA], avB[PA];
#pragma unroll
  for (int p = 0; p < PA; p++) {
    int row = p * 32 + srow;
    avA[p] = *(const bf16x8*)(A + (size_t)(m0 + row) * K_ + scol);
  }
#pragma unroll
  for (int c = 0; c < NC; c++) {
    const bf16x8* av = (c & 1) ? avB : avA;
    bf16x8* avN = (c & 1) ? avA : avB;
    if (c + 1 < NC) {  // prefetch next A chunk (overlaps this chunk's compute)
#pragma unroll
      for (int p = 0; p < PA; p++) {
        int row = p * 32 + srow;
        avN[p] = *(const bf16x8*)(A + (size_t)(m0 + row) * K_ + (c + 1) * 64 + scol);
      }
    }
    bf16x8 bv[4];
#pragma unroll
    for (int p = 0; p < 4; p++) {
      int row = p * 32 + srow;
      bv[p] = *(const bf16x8*)(B + (size_t)(n0 + row) * K_ + c * 64 + scol);
    }
    __syncthreads();  // prev iter's LDS reads done
#pragma unroll
    for (int p = 0; p < PA; p++)
      *(bf16x8*)&As[(p * 32 + srow) * 72 + scol] = av[p];
#pragma unroll
    for (int p = 0; p < 4; p++)
      *(bf16x8*)&Bs[(p * 32 + srow) * 72 + scol] = bv[p];
    __syncthreads();
#pragma unroll
    for (int ks = 0; ks < 2; ks++) {
      bf16x8 a[MI], b[4];
#pragma unroll
      for (int i = 0; i < MI; i++)
        a[i] = *(const bf16x8*)&As[(wr + i * 16 + l15) * 72 + ks * 32 + quad * 8];
#pragma unroll
      for (int j = 0; j < 4; j++)
        b[j] = *(const bf16x8*)&Bs[(wc + j * 16 + l15) * 72 + ks * 32 + quad * 8];
#pragma unroll
      for (int i = 0; i < MI; i++)
#pragma unroll
        for (int j = 0; j < 4; j++)
          acc[i][j] =
              __builtin_amdgcn_mfma_f32_16x16x32_bf16(a[i], b[j], acc[i][j], 0, 0, 0);
    }
  }
  // q scale folded with log2e for exp2-domain softmax downstream
  const float qscale = 0.17677669529663687f * LOG2E;
#pragma unroll
  for (int i = 0; i < MI; i++) {
#pragma unroll
    for (int r = 0; r < 4; r++) {
      int tok = m0 + wr + i * 16 + quad * 4 + r;
      size_t obase = 0;
      if constexpr (EPI == 1) {
        int win = tok >> 9, pos = tok & 511;
        int rd = (win >> 6) * 8 + (pos >> 6);
        int rh = ((win >> 3) & 7) * 8 + ((pos >> 3) & 7);
        int rw = (win & 7) * 8 + (pos & 7);
        int od = (rd + 4) & 15, oh = (rh + 4) & 63, ow = (rw + 4) & 63;
        obase = (size_t)((od * 64 + oh) * 64 + ow) * 128;
      } else if constexpr (EPI != 0) {
        obase = (size_t)tok * N_;
      }
#pragma unroll
      for (int j = 0; j < 4; j++) {
        int gn = n0 + wc + j * 16 + l15;
        float v = acc[i][j][r] + (float)bias[gn];
        if constexpr (EPI == 0) {
          int tensor = gn >> 7, c = gn & 127, head = c >> 5, d = c & 31;
          if (tensor == 0) v *= qscale;
          int win = tok >> 9, pos = tok & 511;
          size_t off = ((((size_t)tensor * 4 + head) * 128 + win) * 512 + pos) * 32 + d;
          ((bf16*)outv)[off] = (bf16)v;
        } else if constexpr (EPI == 1) {
          v += (float)resid[obase + gn];
          ((bf16*)outv)[obase + gn] = (bf16)v;
        } else if constexpr (EPI == 2) {
          // tanh-GELU via native exp2: g = v - v/(exp2(u2)+1)
          float v2 = v * v;
          float u2 = v * (2.30220806f + 0.10294323f * v2);
          float e2 = exp2f(u2);
          float rcp = __builtin_amdgcn_rcpf(e2 + 1.f);
          v = v - v * rcp;
          ((bf16*)outv)[obase + gn] = (bf16)v;
        } else {
          v += (float)resid[obase + gn];
          if (fl)
            ((bf16*)outv)[obase + gn] = (bf16)v;
          else
            ((float*)outv)[obase + gn] = v;
        }
      }
    }
  }
}

// ---------------------------------------------------------------------------
// Fused window attention, S^T formulation, exp2-domain softmax, BARRIER-FREE
// K-loop (R6 structure: V^T staged ONCE, 33 KB; sP per-wave; one barrier).
// Block = (window, head, 128-query chunk). qkv head-major
// [tensor][head][win][pos][32]. q and rpe pre-scaled by log2e.
// ---------------------------------------------------------------------------
__global__ __launch_bounds__(256) void attn_k(const bf16* __restrict__ qkv,
                                              const bf16* __restrict__ rpe,
                                              bf16* __restrict__ att) {
  __shared__ __align__(16) bf16 sVt[32 * 520];   // V^T [d][key], 520 = 512+8
  __shared__ __align__(16) bf16 sP[4][32 * 72];  // per-wave P^T [q][key]
  __shared__ __align__(4) unsigned char lbl[512];
  const int t = threadIdx.x;
  const int p = blockIdx.x;
  const int win = ((p >> 7) << 3) | (p & 7);
  const int j = (p >> 3) & 15;
  const int head = j >> 2, qc = j & 3;
  const int wave = t >> 6, lane = t & 63, l15 = lane & 15, quad = lane >> 4;

  const int wd = win >> 6, wh = (win >> 3) & 7, ww = win & 7;
  const bool wm = (wd == 1) || (wh == 7) || (ww == 7);  // boundary window?
  if (wm) {  // region labels: per-axis boundaries at size-8, size-4
    for (int pp = t; pp < 512; pp += 256) {
      int gd = wd * 8 + (pp >> 6), gh = wh * 8 + ((pp >> 3) & 7),
          gw = ww * 8 + (pp & 7);
      int ld = gd < 8 ? 0 : (gd < 12 ? 1 : 2);
      int lh = gh < 56 ? 0 : (gh < 60 ? 1 : 2);
      int lw = gw < 56 ? 0 : (gw < 60 ? 1 : 2);
      lbl[pp] = (unsigned char)((ld << 4) | (lh << 2) | lw);
    }
  }

  const size_t hw32 = (size_t)512 * 32;
  const bf16* qp = qkv + ((size_t)(0 * 4 + head) * 128 + win) * hw32;
  const bf16* kp = qkv + ((size_t)(1 * 4 + head) * 128 + win) * hw32;
  const bf16* vp = qkv + ((size_t)(2 * 4 + head) * 128 + win) * hw32;
  const bf16* rpeh = rpe + (size_t)head * 512 * 512;
  const int qbase = qc * 128 + wave * 32;

  {  // stage full V^T once: paired-key u32 writes (4-way max conflicts)
    int kpi = t >> 3, dblk = (t & 7) * 4;
    unsigned* s32 = (unsigned*)sVt;
#pragma unroll
    for (int kb = 0; kb < 8; kb++) {
      const bf16* v0 = vp + (size_t)(kb * 64 + 2 * kpi) * 32 + dblk;
      bf16x4 a = *(const bf16x4*)v0;
      bf16x4 b = *(const bf16x4*)(v0 + 32);
      int keyw = (kb * 64 + 2 * kpi) >> 1;
#pragma unroll
      for (int dd = 0; dd < 4; dd++) {
        unsigned wv = (unsigned)__builtin_bit_cast(u16, a[dd]) |
                      ((unsigned)__builtin_bit_cast(u16, b[dd]) << 16);
        s32[(dblk + dd) * 260 + keyw] = wv;
      }
    }
  }

  // Q fragments (B operand): lane n=l15 -> query, k=quad*8+j -> d
  bf16x8 qa[2];
#pragma unroll
  for (int nt = 0; nt < 2; nt++)
    qa[nt] = *(const bf16x8*)(qp + (size_t)(qbase + nt * 16 + l15) * 32 + quad * 8);

  __syncthreads();  // the ONLY block-wide barrier

  int lq[2] = {0, 0};
  if (wm) {
#pragma unroll
    for (int nt = 0; nt < 2; nt++) lq[nt] = lbl[qbase + nt * 16 + l15];
  }

  f32x4 O[2][2] = {};  // O^T tiles [dm][nt]
  float ms[2] = {-1e30f, -1e30f}, ls[2] = {0.f, 0.f};
  bf16* pw = sP[wave];

  for (int kt = 0; kt < 8; kt++) {
    // S^T = K·Q^T with C initialized to rpe (+mask). A=K frags from global.
    f32x4 S[4][2];
#pragma unroll
    for (int mt = 0; mt < 4; mt++) {
      bf16x8 kb =
          *(const bf16x8*)(kp + (size_t)(kt * 64 + mt * 16 + l15) * 32 + quad * 8);
      int kcb = kt * 64 + mt * 16 + quad * 4;
      unsigned kl4 = 0;
      if (wm) kl4 = *(const unsigned*)&lbl[kcb];
#pragma unroll
      for (int nt = 0; nt < 2; nt++) {
        bf16x4 rv =
            *(const bf16x4*)(rpeh + (size_t)(qbase + nt * 16 + l15) * 512 + kcb);
        f32x4 c;
#pragma unroll
        for (int r = 0; r < 4; r++) {
          float bv = (float)rv[r];
          if (wm && (int)((kl4 >> (8 * r)) & 0xFF) != lq[nt]) bv -= 144.269504f;
          c[r] = bv;
        }
        S[mt][nt] = __builtin_amdgcn_mfma_f32_16x16x32_bf16(kb, qa[nt], c, 0, 0, 0);
      }
    }
    // online softmax (exp2 domain): query = l15; keys over (mt, r, quad)
#pragma unroll
    for (int nt = 0; nt < 2; nt++) {
      float mx = -1e30f;
#pragma unroll
      for (int mt = 0; mt < 4; mt++)
#pragma unroll
        for (int r = 0; r < 4; r++) mx = fmaxf(mx, S[mt][nt][r]);
      mx = fmaxf(mx, __shfl_xor(mx, 16));
      mx = fmaxf(mx, __shfl_xor(mx, 32));
      float mnew = fmaxf(ms[nt], mx);
      float alpha = exp2f(ms[nt] - mnew);
      ms[nt] = mnew;
      float rs = 0.f;
#pragma unroll
      for (int mt = 0; mt < 4; mt++)
#pragma unroll
        for (int r = 0; r < 4; r++) {
          float pe = exp2f(S[mt][nt][r] - mnew);
          S[mt][nt][r] = pe;
          rs += pe;
        }
      rs += __shfl_xor(rs, 16);
      rs += __shfl_xor(rs, 32);
      ls[nt] = ls[nt] * alpha + rs;
      O[0][nt] *= alpha;
      O[1][nt] *= alpha;
    }
    // P store: lane holds (query=l15, 4 consecutive keys) -> b64 packed
#pragma unroll
    for (int nt = 0; nt < 2; nt++)
#pragma unroll
      for (int mt = 0; mt < 4; mt++) {
        bf16x4 pv;
#pragma unroll
        for (int r = 0; r < 4; r++) pv[r] = (bf16)S[mt][nt][r];
        *(bf16x4*)&pw[(nt * 16 + l15) * 72 + mt * 16 + quad * 4] = pv;
      }
    // O^T += V^T · P  (sVt read-only; pw per-wave)
#pragma unroll
    for (int s = 0; s < 2; s++) {
      bf16x8 va0 = *(const bf16x8*)&sVt[l15 * 520 + kt * 64 + s * 32 + quad * 8];
      bf16x8 va1 =
          *(const bf16x8*)&sVt[(16 + l15) * 520 + kt * 64 + s * 32 + quad * 8];
      bf16x8 pb0 = *(const bf16x8*)&pw[l15 * 72 + s * 32 + quad * 8];
      bf16x8 pb1 = *(const bf16x8*)&pw[(16 + l15) * 72 + s * 32 + quad * 8];
      O[0][0] = __builtin_amdgcn_mfma_f32_16x16x32_bf16(va0, pb0, O[0][0], 0, 0, 0);
      O[0][1] = __builtin_amdgcn_mfma_f32_16x16x32_bf16(va0, pb1, O[0][1], 0, 0, 0);
      O[1][0] = __builtin_amdgcn_mfma_f32_16x16x32_bf16(va1, pb0, O[1][0], 0, 0, 0);
      O[1][1] = __builtin_amdgcn_mfma_f32_16x16x32_bf16(va1, pb1, O[1][1], 0, 0, 0);
    }
  }
  // epilogue: lane = query l15, regs = d (quad*4+r) -> b64 writes
#pragma unroll
  for (int nt = 0; nt < 2; nt++) {
    float inv = __builtin_amdgcn_rcpf(ls[nt]);
    int q = qbase + nt * 16 + l15;
#pragma unroll
    for (int dm = 0; dm < 2; dm++) {
      bf16x4 o;
#pragma unroll
      for (int r = 0; r < 4; r++) o[r] = (bf16)(O[dm][nt][r] * inv);
      *(bf16x4*)(att + ((size_t)win * 512 + q) * 128 + head * 32 + dm * 16 +
                 quad * 4) = o;
    }
  }
}

// ---------------------------------------------------------------------------
extern "C" void kernel_launch(void* const* d_in, const int* in_sizes, int n_in,
                              void* d_out, int out_size, void* d_ws,
                              size_t ws_size, hipStream_t stream) {
  const int* rel_index = (const int*)d_in[2];
  char* w = (char*)d_ws;

  int* flag = (int*)w;
  bf16* rb_c = (bf16*)(w + (64ull << 10));
  bf16* qw_c = (bf16*)(w + (128ull << 10));
  bf16* pw_c = (bf16*)(w + (256ull << 10));
  bf16* w1_c = (bf16*)(w + (320ull << 10));
  bf16* w2_c = (bf16*)(w + (512ull << 10));
  bf16* qb_c = (bf16*)(w + (704ull << 10));
  bf16* pb_c = (bf16*)(w + (708ull << 10));
  bf16* g1_c = (bf16*)(w + (712ull << 10));
  bf16* b1n_c = (bf16*)(w + (716ull << 10));
  bf16* g2_c = (bf16*)(w + (720ull << 10));
  bf16* b2n_c = (bf16*)(w + (724ull << 10));
  bf16* mb1_c = (bf16*)(w + (728ull << 10));
  bf16* mb2_c = (bf16*)(w + (732ull << 10));
  bf16* x_c = (bf16*)(w + (1ull << 20));    // [1,17) MB
  bf16* xw = (bf16*)(w + (17ull << 20));    // [17,33) MB; reused: att, h2
  bf16* qkvb = (bf16*)(w + (33ull << 20));  // [33,97) MB; reused: a1
  bf16* rpe = (bf16*)(w + (97ull << 20));   // [97,99) MB
  bf16* x2 = (bf16*)(w + (99ull << 20));    // [99,115) MB
  bf16* att = xw;
  bf16* h2 = xw;
  bf16* a1 = qkvb;

  sniff_k<<<1, 64, 0, stream>>>((const unsigned*)d_in[0], flag);
  canon_big_k<<<4096, 256, 0, stream>>>(d_in[0], x_c, flag);

  CanonArgs ca;
  const int srcidx[13] = {3, 4, 5, 6, 7, 8, 9, 10, 11, 12, 13, 14, 15};
  bf16* dsts[13] = {rb_c, qw_c, qb_c, pw_c, pb_c, g1_c, b1n_c,
                    g2_c, b2n_c, w1_c, mb1_c, w2_c, mb2_c};
  for (int i = 0; i < 13; i++) {
    ca.src[i] = d_in[srcidx[i]];
    ca.dst[i] = dsts[i];
    ca.n[i] = in_sizes[srcidx[i]];
  }
  canon_small_k<<<dim3(256, 13), 256, 0, stream>>>(ca, flag);

  rpe_k<<<4096, 256, 0, stream>>>(rel_index, rb_c, rpe);
  ln_k<1><<<16384, 256, 0, stream>>>(x_c, g1_c, b1n_c, xw);
  gemm_k<0, 128, 384, 128><<<dim3(512, 3), 256, 0, stream>>>(xw, qw_c, qb_c,
                                                             qkvb, nullptr, flag);
  attn_k<<<2048, 256, 0, stream>>>(qkvb, rpe, att);
  gemm_k<1, 64, 128, 128><<<dim3(1024, 1), 256, 0, stream>>>(att, pw_c, pb_c,
                                                             x2, x_c, flag);
  ln_k<0><<<16384, 256, 0, stream>>>(x2, g2_c, b2n_c, h2);
  gemm_k<2, 128, 512, 128><<<dim3(512, 4), 256, 0, stream>>>(h2, w1_c, mb1_c,
                                                             a1, nullptr, flag);
  gemm_k<3, 64, 128, 512><<<dim3(1024, 1), 256, 0, stream>>>(a1, w2_c, mb2_c,
                                                             d_out, x2, flag);
}